// Round 1
// baseline (642.856 us; speedup 1.0000x reference)
//
#include <hip/hip_runtime.h>
#include <math.h>

// Problem constants (from reference): IN_DIM=128, HEADS=8, HEAD_DIM=16,
// HEADS*HEAD_DIM=128. Output [N, 8, 16] fp32 flat = N*128.
#define DIM 128
#define N_HEADS 8
#define HD 16

// ---------------------------------------------------------------------------
// QKV projection: Q/K/V[n][c] = sum_k h[n][k] * W[k][c] + b[c]
// Tile: 64 nodes x 128 cols per 256-thread block; per-thread 4 nodes x 8 cols.
// h tile staged in LDS with stride 129 (pad +1 breaks the stride-128
// power-of-2 bank aliasing on the per-k reads).
// ---------------------------------------------------------------------------
__global__ __launch_bounds__(256)
void qkv_kernel(const float* __restrict__ h,
                const float* __restrict__ WQ, const float* __restrict__ bQ,
                const float* __restrict__ WK, const float* __restrict__ bK,
                const float* __restrict__ WV, const float* __restrict__ bV,
                float* __restrict__ Q, float* __restrict__ K, float* __restrict__ V,
                int N)
{
    __shared__ float hs[64 * 129];
    const int n0  = blockIdx.x * 64;
    const int tid = threadIdx.x;

    // Stage 64x128 h tile (coalesced global reads, conflict-free LDS writes).
    #pragma unroll
    for (int i = 0; i < 32; ++i) {
        int idx  = i * 256 + tid;          // 0..8191
        int node = idx >> 7;
        int k    = idx & 127;
        int gn   = n0 + node;
        hs[node * 129 + k] = (gn < N) ? h[(size_t)gn * DIM + k] : 0.0f;
    }
    __syncthreads();

    const int cg = tid & 15;   // col group  -> cols c0..c0+7
    const int ng = tid >> 4;   // node group -> nodes ng*4..ng*4+3
    const int c0 = cg * 8;

    const float* Ws[3] = {WQ, WK, WV};
    const float* bs[3] = {bQ, bK, bV};
    float*       Os[3] = {Q, K, V};

    for (int m = 0; m < 3; ++m) {
        const float* __restrict__ W = Ws[m];
        const float* __restrict__ b = bs[m];
        float acc[4][8];
        #pragma unroll
        for (int i = 0; i < 8; ++i) {
            float bi = b[c0 + i];
            #pragma unroll
            for (int j = 0; j < 4; ++j) acc[j][i] = bi;
        }

        #pragma unroll 2
        for (int k = 0; k < DIM; ++k) {
            float4 w0 = *(const float4*)(W + k * DIM + c0);
            float4 w1 = *(const float4*)(W + k * DIM + c0 + 4);
            float hv[4];
            #pragma unroll
            for (int j = 0; j < 4; ++j) hv[j] = hs[(ng * 4 + j) * 129 + k];
            #pragma unroll
            for (int j = 0; j < 4; ++j) {
                acc[j][0] += hv[j] * w0.x;
                acc[j][1] += hv[j] * w0.y;
                acc[j][2] += hv[j] * w0.z;
                acc[j][3] += hv[j] * w0.w;
                acc[j][4] += hv[j] * w1.x;
                acc[j][5] += hv[j] * w1.y;
                acc[j][6] += hv[j] * w1.z;
                acc[j][7] += hv[j] * w1.w;
            }
        }

        float* __restrict__ O = Os[m];
        #pragma unroll
        for (int j = 0; j < 4; ++j) {
            int gn = n0 + ng * 4 + j;
            if (gn < N) {
                float4 o0 = make_float4(acc[j][0], acc[j][1], acc[j][2], acc[j][3]);
                float4 o1 = make_float4(acc[j][4], acc[j][5], acc[j][6], acc[j][7]);
                *(float4*)(O + (size_t)gn * DIM + c0)     = o0;
                *(float4*)(O + (size_t)gn * DIM + c0 + 4) = o1;
            }
        }
        __syncthreads();  // no-op safety between matrices (hs reused read-only)
    }
}

// ---------------------------------------------------------------------------
// Edge phase: per edge e, per head: s = K[src]·Q[dst]/4, w = exp(clamp(s,-5,5)),
// atomically scatter w*V[src] into out[dst] and w into z[dst].
// 128 threads per edge (one per (head,dim)); 2 edges per 256-thread block.
// Head dot via 16-lane shuffle butterfly (head groups lie within one wave).
// ---------------------------------------------------------------------------
__global__ __launch_bounds__(256)
void edge_kernel(const int* __restrict__ src, const int* __restrict__ dst,
                 const float* __restrict__ Q, const float* __restrict__ K,
                 const float* __restrict__ V,
                 float* __restrict__ z, float* __restrict__ out, int E)
{
    const int t = threadIdx.x;
    const long long e = (long long)blockIdx.x * 2 + (t >> 7);
    if (e >= E) return;
    const int lane = t & 127;

    const int s = src[e];
    const int d = dst[e];

    const float kv = K[(size_t)s * DIM + lane];
    const float qv = Q[(size_t)d * DIM + lane];
    float p = kv * qv;
    // reduce across the 16 lanes of this head (xor of low 4 bits stays in-group)
    p += __shfl_xor(p, 8);
    p += __shfl_xor(p, 4);
    p += __shfl_xor(p, 2);
    p += __shfl_xor(p, 1);

    float sc = p * 0.25f;                       // / sqrt(16)
    sc = fminf(fmaxf(sc, -5.0f), 5.0f);
    const float w = __expf(sc);

    const float vv = V[(size_t)s * DIM + lane];
    atomicAdd(out + (size_t)d * DIM + lane, vv * w);
    if ((lane & 15) == 0)
        atomicAdd(z + (size_t)d * N_HEADS + (lane >> 4), w);
}

// ---------------------------------------------------------------------------
// Finalize: out = (z > 0) ? out / z : out
// ---------------------------------------------------------------------------
__global__ __launch_bounds__(256)
void finalize_kernel(const float* __restrict__ z, float* __restrict__ out,
                     long long total)
{
    long long i = (long long)blockIdx.x * 256 + threadIdx.x;
    if (i >= total) return;
    int n  = (int)(i >> 7);
    int hd = (int)((i >> 4) & 7);
    float zz = z[(size_t)n * N_HEADS + hd];
    if (zz > 0.0f) out[i] = out[i] / zz;
}

extern "C" void kernel_launch(void* const* d_in, const int* in_sizes, int n_in,
                              void* d_out, int out_size, void* d_ws, size_t ws_size,
                              hipStream_t stream) {
    const float* h   = (const float*)d_in[0];
    const int*   src = (const int*)  d_in[1];
    const int*   dst = (const int*)  d_in[2];
    const float* WQ  = (const float*)d_in[3];
    const float* bQ  = (const float*)d_in[4];
    const float* WK  = (const float*)d_in[5];
    const float* bK  = (const float*)d_in[6];
    const float* WV  = (const float*)d_in[7];
    const float* bV  = (const float*)d_in[8];
    float* out = (float*)d_out;

    const int N = in_sizes[0] / DIM;
    const int E = in_sizes[1];

    // Workspace: Q | K | V | z   (3*N*128 + N*8 floats = 78.4 MB at N=50000)
    float* Q = (float*)d_ws;
    float* K = Q + (size_t)N * DIM;
    float* V = K + (size_t)N * DIM;
    float* z = V + (size_t)N * DIM;

    // d_out and d_ws are poisoned before every timed call — zero accumulators.
    hipMemsetAsync(out, 0, (size_t)N * DIM * sizeof(float), stream);
    hipMemsetAsync(z,   0, (size_t)N * N_HEADS * sizeof(float), stream);

    qkv_kernel<<<(N + 63) / 64, 256, 0, stream>>>(h, WQ, bQ, WK, bK, WV, bV,
                                                  Q, K, V, N);
    edge_kernel<<<(E + 1) / 2, 256, 0, stream>>>(src, dst, Q, K, V, z, out, E);

    const long long total = (long long)N * DIM;
    finalize_kernel<<<(int)((total + 255) / 256), 256, 0, stream>>>(z, out, total);
}

// Round 2
// 359.894 us; speedup vs baseline: 1.7862x; 1.7862x over previous
//
#include <hip/hip_runtime.h>
#include <math.h>

// Problem constants: IN_DIM=128, HEADS=8, HEAD_DIM=16, HEADS*HEAD_DIM=128.
#define DIM 128
#define N_HEADS 8
#define HD 16

// ---------------------------------------------------------------------------
// bf16 helpers (RNE pack, cheap unpack)
// ---------------------------------------------------------------------------
__device__ __forceinline__ unsigned bf16pack2(float a, float b) {
    unsigned ua = __builtin_bit_cast(unsigned, a);
    unsigned ub = __builtin_bit_cast(unsigned, b);
    ua = (ua + 0x7FFFu + ((ua >> 16) & 1u)) >> 16;
    ub = (ub + 0x7FFFu + ((ub >> 16) & 1u)) >> 16;
    return ua | (ub << 16);
}
__device__ __forceinline__ float bf16lo(unsigned p) {
    return __builtin_bit_cast(float, p << 16);
}
__device__ __forceinline__ float bf16hi(unsigned p) {
    return __builtin_bit_cast(float, p & 0xFFFF0000u);
}

// ---------------------------------------------------------------------------
// QKV projection. Q stored fp32 [N,128]. K,V stored bf16 interleaved:
// KV row n = 512 B: [K bf16 x128 | V bf16 x128] -> gather locality + half traffic.
// Tile: 64 nodes x 128 cols per 256-thread block; per-thread 4 nodes x 8 cols.
// ---------------------------------------------------------------------------
__global__ __launch_bounds__(256)
void qkv_kernel(const float* __restrict__ h,
                const float* __restrict__ WQ, const float* __restrict__ bQ,
                const float* __restrict__ WK, const float* __restrict__ bK,
                const float* __restrict__ WV, const float* __restrict__ bV,
                float* __restrict__ Q, unsigned short* __restrict__ KV,
                int N)
{
    __shared__ float hs[64 * 129];
    const int n0  = blockIdx.x * 64;
    const int tid = threadIdx.x;

    #pragma unroll
    for (int i = 0; i < 32; ++i) {
        int idx  = i * 256 + tid;
        int node = idx >> 7;
        int k    = idx & 127;
        int gn   = n0 + node;
        hs[node * 129 + k] = (gn < N) ? h[(size_t)gn * DIM + k] : 0.0f;
    }
    __syncthreads();

    const int cg = tid & 15;   // col group  -> cols c0..c0+7
    const int ng = tid >> 4;   // node group -> nodes ng*4..ng*4+3
    const int c0 = cg * 8;

    const float* Ws[3] = {WQ, WK, WV};
    const float* bs[3] = {bQ, bK, bV};

    for (int m = 0; m < 3; ++m) {
        const float* __restrict__ W = Ws[m];
        const float* __restrict__ b = bs[m];
        float acc[4][8];
        #pragma unroll
        for (int i = 0; i < 8; ++i) {
            float bi = b[c0 + i];
            #pragma unroll
            for (int j = 0; j < 4; ++j) acc[j][i] = bi;
        }

        #pragma unroll 2
        for (int k = 0; k < DIM; ++k) {
            float4 w0 = *(const float4*)(W + k * DIM + c0);
            float4 w1 = *(const float4*)(W + k * DIM + c0 + 4);
            float hv[4];
            #pragma unroll
            for (int j = 0; j < 4; ++j) hv[j] = hs[(ng * 4 + j) * 129 + k];
            #pragma unroll
            for (int j = 0; j < 4; ++j) {
                acc[j][0] += hv[j] * w0.x;
                acc[j][1] += hv[j] * w0.y;
                acc[j][2] += hv[j] * w0.z;
                acc[j][3] += hv[j] * w0.w;
                acc[j][4] += hv[j] * w1.x;
                acc[j][5] += hv[j] * w1.y;
                acc[j][6] += hv[j] * w1.z;
                acc[j][7] += hv[j] * w1.w;
            }
        }

        #pragma unroll
        for (int j = 0; j < 4; ++j) {
            int gn = n0 + ng * 4 + j;
            if (gn >= N) continue;
            if (m == 0) {
                *(float4*)(Q + (size_t)gn * DIM + c0) =
                    make_float4(acc[j][0], acc[j][1], acc[j][2], acc[j][3]);
                *(float4*)(Q + (size_t)gn * DIM + c0 + 4) =
                    make_float4(acc[j][4], acc[j][5], acc[j][6], acc[j][7]);
            } else {
                uint4 p = make_uint4(bf16pack2(acc[j][0], acc[j][1]),
                                     bf16pack2(acc[j][2], acc[j][3]),
                                     bf16pack2(acc[j][4], acc[j][5]),
                                     bf16pack2(acc[j][6], acc[j][7]));
                int off = (m == 1) ? c0 : (128 + c0);
                *(uint4*)(KV + (size_t)gn * 256 + off) = p;
            }
        }
        __syncthreads();
    }
}

// ---------------------------------------------------------------------------
// Counting sort of edges by dst: histogram -> 2-level exclusive scan -> scatter
// ---------------------------------------------------------------------------
__global__ __launch_bounds__(256)
void hist_kernel(const int* __restrict__ dst, int* __restrict__ offs, int E)
{
    int e = blockIdx.x * 256 + threadIdx.x;
    if (e < E) atomicAdd(&offs[dst[e]], 1);
}

__global__ __launch_bounds__(256)
void scan_blocks_kernel(int* __restrict__ offs, int* __restrict__ bsum, int N)
{
    __shared__ int sd[256];
    const int t = threadIdx.x;
    const int i = blockIdx.x * 256 + t;
    int v = (i < N) ? offs[i] : 0;
    sd[t] = v;
    __syncthreads();
    #pragma unroll
    for (int o = 1; o < 256; o <<= 1) {
        int x = (t >= o) ? sd[t - o] : 0;
        __syncthreads();
        sd[t] += x;
        __syncthreads();
    }
    int incl = sd[t];
    if (i < N) offs[i] = incl - v;            // block-local exclusive
    if (t == 255) bsum[blockIdx.x] = incl;    // block total
}

__global__ __launch_bounds__(256)
void scan_bsum_kernel(int* __restrict__ bsum, int nb)
{
    __shared__ int sd[256];
    const int t = threadIdx.x;
    int v = (t < nb) ? bsum[t] : 0;
    sd[t] = v;
    __syncthreads();
    #pragma unroll
    for (int o = 1; o < 256; o <<= 1) {
        int x = (t >= o) ? sd[t - o] : 0;
        __syncthreads();
        sd[t] += x;
        __syncthreads();
    }
    if (t < nb) bsum[t] = sd[t] - v;          // exclusive
}

__global__ __launch_bounds__(256)
void scan_fixup_kernel(int* __restrict__ offs, int* __restrict__ cursor,
                       const int* __restrict__ bsum, int N, int E)
{
    int i = blockIdx.x * 256 + threadIdx.x;
    if (i < N) {
        int v = offs[i] + bsum[blockIdx.x];
        offs[i]   = v;
        cursor[i] = v;
    }
    if (i == 0) offs[N] = E;
}

__global__ __launch_bounds__(256)
void scatter_kernel(const int* __restrict__ src, const int* __restrict__ dst,
                    int* __restrict__ cursor, int* __restrict__ srcs, int E)
{
    int e = blockIdx.x * 256 + threadIdx.x;
    if (e < E) {
        int d   = dst[e];
        int pos = atomicAdd(&cursor[d], 1);
        srcs[pos] = src[e];
    }
}

// ---------------------------------------------------------------------------
// Aggregate: one wave (64 lanes) per dst node; lane owns elements 2l,2l+1
// (head = l>>3). Per bucket edge: gather K,V bf16 pairs, 8-lane shuffle dot,
// exp(clamp(score/4)), accumulate w*V and z in registers. Single final
// divided store -> zero atomics, output written exactly once.
// ---------------------------------------------------------------------------
__global__ __launch_bounds__(256)
void aggregate_kernel(const int* __restrict__ offs, const int* __restrict__ srcs,
                      const float* __restrict__ Q, const unsigned* __restrict__ KVu,
                      float* __restrict__ out, int N)
{
    const int node = blockIdx.x * 4 + (threadIdx.x >> 6);
    if (node >= N) return;
    const int l = threadIdx.x & 63;

    const float2 q = *(const float2*)(Q + (size_t)node * DIM + 2 * l);
    const int start = offs[node];
    const int end   = offs[node + 1];

    float ax = 0.0f, ay = 0.0f, zs = 0.0f;

    int e = start;
    for (; e + 2 <= end; e += 2) {
        int s0 = srcs[e];
        int s1 = srcs[e + 1];
        unsigned k0 = KVu[(size_t)s0 * 128 + l];
        unsigned v0 = KVu[(size_t)s0 * 128 + 64 + l];
        unsigned k1 = KVu[(size_t)s1 * 128 + l];
        unsigned v1 = KVu[(size_t)s1 * 128 + 64 + l];

        float p0 = bf16lo(k0) * q.x + bf16hi(k0) * q.y;
        p0 += __shfl_xor(p0, 4);
        p0 += __shfl_xor(p0, 2);
        p0 += __shfl_xor(p0, 1);
        p0 = fminf(fmaxf(p0 * 0.25f, -5.0f), 5.0f);
        float w0 = __expf(p0);
        ax += w0 * bf16lo(v0);
        ay += w0 * bf16hi(v0);
        zs += w0;

        float p1 = bf16lo(k1) * q.x + bf16hi(k1) * q.y;
        p1 += __shfl_xor(p1, 4);
        p1 += __shfl_xor(p1, 2);
        p1 += __shfl_xor(p1, 1);
        p1 = fminf(fmaxf(p1 * 0.25f, -5.0f), 5.0f);
        float w1 = __expf(p1);
        ax += w1 * bf16lo(v1);
        ay += w1 * bf16hi(v1);
        zs += w1;
    }
    if (e < end) {
        int s0 = srcs[e];
        unsigned k0 = KVu[(size_t)s0 * 128 + l];
        unsigned v0 = KVu[(size_t)s0 * 128 + 64 + l];
        float p0 = bf16lo(k0) * q.x + bf16hi(k0) * q.y;
        p0 += __shfl_xor(p0, 4);
        p0 += __shfl_xor(p0, 2);
        p0 += __shfl_xor(p0, 1);
        p0 = fminf(fmaxf(p0 * 0.25f, -5.0f), 5.0f);
        float w0 = __expf(p0);
        ax += w0 * bf16lo(v0);
        ay += w0 * bf16hi(v0);
        zs += w0;
    }

    float inv = (zs > 0.0f) ? (1.0f / zs) : 0.0f;
    *(float2*)(out + (size_t)node * DIM + 2 * l) = make_float2(ax * inv, ay * inv);
}

// ---------------------------------------------------------------------------
extern "C" void kernel_launch(void* const* d_in, const int* in_sizes, int n_in,
                              void* d_out, int out_size, void* d_ws, size_t ws_size,
                              hipStream_t stream) {
    const float* h   = (const float*)d_in[0];
    const int*   src = (const int*)  d_in[1];
    const int*   dst = (const int*)  d_in[2];
    const float* WQ  = (const float*)d_in[3];
    const float* bQ  = (const float*)d_in[4];
    const float* WK  = (const float*)d_in[5];
    const float* bK  = (const float*)d_in[6];
    const float* WV  = (const float*)d_in[7];
    const float* bV  = (const float*)d_in[8];
    float* out = (float*)d_out;

    const int N = in_sizes[0] / DIM;
    const int E = in_sizes[1];
    const int NB = (N + 255) / 256;   // scan blocks (196 for N=50000; must be <=256)

    // Workspace layout (bytes):
    //   Q      : N*128 fp32          = 25.6 MB
    //   KV     : N*256 bf16          = 25.6 MB
    //   offs   : (N+1) int
    //   cursor : N int
    //   bsum   : 256 int
    //   srcs   : E int               = 3.2 MB          total ~54.8 MB
    char* w = (char*)d_ws;
    float*          Q      = (float*)w;           w += (size_t)N * DIM * sizeof(float);
    unsigned short* KV     = (unsigned short*)w;  w += (size_t)N * 256 * sizeof(unsigned short);
    int*            offs   = (int*)w;             w += (size_t)(N + 1) * sizeof(int);
    int*            cursor = (int*)w;             w += (size_t)N * sizeof(int);
    int*            bsum   = (int*)w;             w += 256 * sizeof(int);
    int*            srcs   = (int*)w;

    hipMemsetAsync(offs, 0, (size_t)(N + 1) * sizeof(int), stream);

    qkv_kernel<<<(N + 63) / 64, 256, 0, stream>>>(h, WQ, bQ, WK, bK, WV, bV,
                                                  Q, KV, N);
    hist_kernel<<<(E + 255) / 256, 256, 0, stream>>>(dst, offs, E);
    scan_blocks_kernel<<<NB, 256, 0, stream>>>(offs, bsum, N);
    scan_bsum_kernel<<<1, 256, 0, stream>>>(bsum, NB);
    scan_fixup_kernel<<<NB, 256, 0, stream>>>(offs, cursor, bsum, N, E);
    scatter_kernel<<<(E + 255) / 256, 256, 0, stream>>>(src, dst, cursor, srcs, E);
    aggregate_kernel<<<(N + 3) / 4, 256, 0, stream>>>(offs, srcs, Q,
                                                      (const unsigned*)KV, out, N);
}

// Round 3
// 276.683 us; speedup vs baseline: 2.3234x; 1.3007x over previous
//
#include <hip/hip_runtime.h>
#include <math.h>

// Problem constants: IN_DIM=128, HEADS=8, HEAD_DIM=16, HEADS*HEAD_DIM=128.
#define DIM 128
#define N_HEADS 8
#define HD 16

typedef __attribute__((ext_vector_type(8))) short bf16x8;   // MFMA A/B frag (4 VGPRs)
typedef __attribute__((ext_vector_type(4))) float f32x4;    // MFMA C/D frag

// ---------------------------------------------------------------------------
// bf16 helpers (RNE pack, cheap unpack)
// ---------------------------------------------------------------------------
__device__ __forceinline__ unsigned bf16pack2(float a, float b) {
    unsigned ua = __builtin_bit_cast(unsigned, a);
    unsigned ub = __builtin_bit_cast(unsigned, b);
    ua = (ua + 0x7FFFu + ((ua >> 16) & 1u)) >> 16;
    ub = (ub + 0x7FFFu + ((ub >> 16) & 1u)) >> 16;
    return ua | (ub << 16);
}
__device__ __forceinline__ float bf16lo(unsigned p) {
    return __builtin_bit_cast(float, p << 16);
}
__device__ __forceinline__ float bf16hi(unsigned p) {
    return __builtin_bit_cast(float, p & 0xFFFF0000u);
}

// ---------------------------------------------------------------------------
// One-time weight prep: WT[c][k] = bf16(W_m[k][c&127]) for c in [0,384)
// (c<128 -> WQ, <256 -> WK, else WV), plus fused bias384[c].
// B-operand fragment wants 8 contiguous k for fixed output col -> transpose.
// ---------------------------------------------------------------------------
__global__ __launch_bounds__(256)
void convert_w_kernel(const float* __restrict__ WQ, const float* __restrict__ bQ,
                      const float* __restrict__ WK, const float* __restrict__ bK,
                      const float* __restrict__ WV, const float* __restrict__ bV,
                      unsigned short* __restrict__ WT, float* __restrict__ bias384)
{
    int idx = blockIdx.x * 256 + threadIdx.x;       // 0..49151
    int c = idx >> 7, k = idx & 127;
    const float* W; const float* b; int col = c & 127;
    if (c < 128)      { W = WQ; b = bQ; }
    else if (c < 256) { W = WK; b = bK; }
    else              { W = WV; b = bV; }
    float v = W[k * DIM + col];
    WT[(size_t)c * DIM + k] = (unsigned short)(bf16pack2(v, 0.0f) & 0xFFFFu);
    if (k == 0) bias384[c] = b[col];
}

// ---------------------------------------------------------------------------
// QKV projection via bf16 MFMA 16x16x32.
// Block = 256 thr = 4 waves, covers 64 nodes x 384 cols. Wave w owns cols
// [w*96, w*96+96) (6 col-tiles) for all 4 row-tiles -> B frags not duplicated.
// h tile staged bf16 in LDS, row stride 136 (pad+8 -> 2-way bank alias, free).
// acc initialized with bias (free bias add). Epilogue: __shfl_xor(1) packs
// adjacent cols -> float2 stores (Q fp32) / dword bf16x2 stores (KV).
// A frag: A[m=lane&15][k=quad*8+j]; B frag: B[k=quad*8+j][n=lane&15] (WT row);
// C/D:    col=lane&15, row=quad*4+reg.
// ---------------------------------------------------------------------------
__global__ __launch_bounds__(256)
void qkv_mfma_kernel(const float* __restrict__ h,
                     const unsigned short* __restrict__ WT,
                     const float* __restrict__ bias384,
                     float* __restrict__ Q, unsigned short* __restrict__ KV,
                     int N)
{
    __shared__ unsigned short hs[64 * 136];
    const int tid = threadIdx.x;
    const int n0  = blockIdx.x * 64;

    // ---- stage 64x128 h tile as bf16 -------------------------------------
    #pragma unroll
    for (int i = 0; i < 4; ++i) {
        int lin  = i * 256 + tid;          // 0..1023
        int node = lin >> 4;               // 0..63
        int k0   = (lin & 15) * 8;         // 0..120
        int gn   = n0 + node;
        float4 a0, a1;
        if (gn < N) {
            a0 = *(const float4*)(h + (size_t)gn * DIM + k0);
            a1 = *(const float4*)(h + (size_t)gn * DIM + k0 + 4);
        } else {
            a0 = make_float4(0.f, 0.f, 0.f, 0.f);
            a1 = a0;
        }
        uint4 p = make_uint4(bf16pack2(a0.x, a0.y), bf16pack2(a0.z, a0.w),
                             bf16pack2(a1.x, a1.y), bf16pack2(a1.z, a1.w));
        *(uint4*)(hs + node * 136 + k0) = p;
    }
    __syncthreads();

    const int wave   = tid >> 6;
    const int l      = tid & 63;
    const int lane16 = l & 15;
    const int quad   = l >> 4;
    const int wc0    = wave * 96;

    // ---- accumulators, bias-initialized ----------------------------------
    f32x4 acc[4][6];
    #pragma unroll
    for (int ct = 0; ct < 6; ++ct) {
        float bv = bias384[wc0 + ct * 16 + lane16];
        #pragma unroll
        for (int rt = 0; rt < 4; ++rt)
            acc[rt][ct] = (f32x4){bv, bv, bv, bv};
    }

    // ---- K loop: 4 steps of 32 -------------------------------------------
    #pragma unroll
    for (int ks = 0; ks < 4; ++ks) {
        bf16x8 a[4], b[6];
        #pragma unroll
        for (int rt = 0; rt < 4; ++rt)
            a[rt] = *(const bf16x8*)(hs + (rt * 16 + lane16) * 136 + ks * 32 + quad * 8);
        #pragma unroll
        for (int ct = 0; ct < 6; ++ct)
            b[ct] = *(const bf16x8*)(WT + (size_t)(wc0 + ct * 16 + lane16) * DIM
                                         + ks * 32 + quad * 8);
        #pragma unroll
        for (int rt = 0; rt < 4; ++rt)
            #pragma unroll
            for (int ct = 0; ct < 6; ++ct)
                acc[rt][ct] = __builtin_amdgcn_mfma_f32_16x16x32_bf16(
                    a[rt], b[ct], acc[rt][ct], 0, 0, 0);
    }

    // ---- epilogue: pack adjacent cols via shuffle, store -----------------
    const bool evenlane = (lane16 & 1) == 0;
    #pragma unroll
    for (int rt = 0; rt < 4; ++rt) {
        #pragma unroll
        for (int ct = 0; ct < 6; ++ct) {
            int col = wc0 + ct * 16 + lane16;
            #pragma unroll
            for (int i = 0; i < 4; ++i) {
                float v  = acc[rt][ct][i];
                float vn = __shfl_xor(v, 1);
                int gn = n0 + rt * 16 + quad * 4 + i;
                if (evenlane && gn < N) {
                    if (col < 128) {
                        *(float2*)(Q + (size_t)gn * DIM + col) = make_float2(v, vn);
                    } else {
                        // KV row: [K bf16 x128 | V bf16 x128]; K cols 128-255,
                        // V cols 256-383 -> offset col-128 in both cases.
                        *(unsigned*)(KV + (size_t)gn * 256 + (col - 128)) =
                            bf16pack2(v, vn);
                    }
                }
            }
        }
    }
}

// ---------------------------------------------------------------------------
// Counting sort of edges by dst: histogram -> 2-level exclusive scan -> scatter
// ---------------------------------------------------------------------------
__global__ __launch_bounds__(256)
void hist_kernel(const int* __restrict__ dst, int* __restrict__ offs, int E)
{
    int e = blockIdx.x * 256 + threadIdx.x;
    if (e < E) atomicAdd(&offs[dst[e]], 1);
}

__global__ __launch_bounds__(256)
void scan_blocks_kernel(int* __restrict__ offs, int* __restrict__ bsum, int N)
{
    __shared__ int sd[256];
    const int t = threadIdx.x;
    const int i = blockIdx.x * 256 + t;
    int v = (i < N) ? offs[i] : 0;
    sd[t] = v;
    __syncthreads();
    #pragma unroll
    for (int o = 1; o < 256; o <<= 1) {
        int x = (t >= o) ? sd[t - o] : 0;
        __syncthreads();
        sd[t] += x;
        __syncthreads();
    }
    int incl = sd[t];
    if (i < N) offs[i] = incl - v;            // block-local exclusive
    if (t == 255) bsum[blockIdx.x] = incl;    // block total
}

__global__ __launch_bounds__(256)
void scan_bsum_kernel(int* __restrict__ bsum, int nb)
{
    __shared__ int sd[256];
    const int t = threadIdx.x;
    int v = (t < nb) ? bsum[t] : 0;
    sd[t] = v;
    __syncthreads();
    #pragma unroll
    for (int o = 1; o < 256; o <<= 1) {
        int x = (t >= o) ? sd[t - o] : 0;
        __syncthreads();
        sd[t] += x;
        __syncthreads();
    }
    if (t < nb) bsum[t] = sd[t] - v;          // exclusive
}

__global__ __launch_bounds__(256)
void scan_fixup_kernel(int* __restrict__ offs, int* __restrict__ cursor,
                       const int* __restrict__ bsum, int N, int E)
{
    int i = blockIdx.x * 256 + threadIdx.x;
    if (i < N) {
        int v = offs[i] + bsum[blockIdx.x];
        offs[i]   = v;
        cursor[i] = v;
    }
    if (i == 0) offs[N] = E;
}

__global__ __launch_bounds__(256)
void scatter_kernel(const int* __restrict__ src, const int* __restrict__ dst,
                    int* __restrict__ cursor, int* __restrict__ srcs, int E)
{
    int e = blockIdx.x * 256 + threadIdx.x;
    if (e < E) {
        int d   = dst[e];
        int pos = atomicAdd(&cursor[d], 1);
        srcs[pos] = src[e];
    }
}

// ---------------------------------------------------------------------------
// Aggregate: one wave (64 lanes) per dst node; lane owns elements 2l,2l+1
// (head = l>>3). Per bucket edge: gather K,V bf16 pairs, 8-lane shuffle dot,
// exp(clamp(score/4)), accumulate w*V and z in registers. Single final
// divided store -> zero atomics, output written exactly once.
// ---------------------------------------------------------------------------
__global__ __launch_bounds__(256)
void aggregate_kernel(const int* __restrict__ offs, const int* __restrict__ srcs,
                      const float* __restrict__ Q, const unsigned* __restrict__ KVu,
                      float* __restrict__ out, int N)
{
    const int node = blockIdx.x * 4 + (threadIdx.x >> 6);
    if (node >= N) return;
    const int l = threadIdx.x & 63;

    const float2 q = *(const float2*)(Q + (size_t)node * DIM + 2 * l);
    const int start = offs[node];
    const int end   = offs[node + 1];

    float ax = 0.0f, ay = 0.0f, zs = 0.0f;

    int e = start;
    for (; e + 2 <= end; e += 2) {
        int s0 = srcs[e];
        int s1 = srcs[e + 1];
        unsigned k0 = KVu[(size_t)s0 * 128 + l];
        unsigned v0 = KVu[(size_t)s0 * 128 + 64 + l];
        unsigned k1 = KVu[(size_t)s1 * 128 + l];
        unsigned v1 = KVu[(size_t)s1 * 128 + 64 + l];

        float p0 = bf16lo(k0) * q.x + bf16hi(k0) * q.y;
        p0 += __shfl_xor(p0, 4);
        p0 += __shfl_xor(p0, 2);
        p0 += __shfl_xor(p0, 1);
        p0 = fminf(fmaxf(p0 * 0.25f, -5.0f), 5.0f);
        float w0 = __expf(p0);
        ax += w0 * bf16lo(v0);
        ay += w0 * bf16hi(v0);
        zs += w0;

        float p1 = bf16lo(k1) * q.x + bf16hi(k1) * q.y;
        p1 += __shfl_xor(p1, 4);
        p1 += __shfl_xor(p1, 2);
        p1 += __shfl_xor(p1, 1);
        p1 = fminf(fmaxf(p1 * 0.25f, -5.0f), 5.0f);
        float w1 = __expf(p1);
        ax += w1 * bf16lo(v1);
        ay += w1 * bf16hi(v1);
        zs += w1;
    }
    if (e < end) {
        int s0 = srcs[e];
        unsigned k0 = KVu[(size_t)s0 * 128 + l];
        unsigned v0 = KVu[(size_t)s0 * 128 + 64 + l];
        float p0 = bf16lo(k0) * q.x + bf16hi(k0) * q.y;
        p0 += __shfl_xor(p0, 4);
        p0 += __shfl_xor(p0, 2);
        p0 += __shfl_xor(p0, 1);
        p0 = fminf(fmaxf(p0 * 0.25f, -5.0f), 5.0f);
        float w0 = __expf(p0);
        ax += w0 * bf16lo(v0);
        ay += w0 * bf16hi(v0);
        zs += w0;
    }

    float inv = (zs > 0.0f) ? (1.0f / zs) : 0.0f;
    *(float2*)(out + (size_t)node * DIM + 2 * l) = make_float2(ax * inv, ay * inv);
}

// ---------------------------------------------------------------------------
extern "C" void kernel_launch(void* const* d_in, const int* in_sizes, int n_in,
                              void* d_out, int out_size, void* d_ws, size_t ws_size,
                              hipStream_t stream) {
    const float* h   = (const float*)d_in[0];
    const int*   src = (const int*)  d_in[1];
    const int*   dst = (const int*)  d_in[2];
    const float* WQ  = (const float*)d_in[3];
    const float* bQ  = (const float*)d_in[4];
    const float* WK  = (const float*)d_in[5];
    const float* bK  = (const float*)d_in[6];
    const float* WV  = (const float*)d_in[7];
    const float* bV  = (const float*)d_in[8];
    float* out = (float*)d_out;

    const int N = in_sizes[0] / DIM;
    const int E = in_sizes[1];
    const int NB = (N + 255) / 256;   // scan blocks (196 for N=50000; must be <=256)

    // Workspace layout:
    //   Q      : N*128 fp32   = 25.6 MB
    //   KV     : N*256 bf16   = 25.6 MB
    //   WT     : 384*128 bf16 = 96 KB
    //   bias384: 384 fp32
    //   offs   : (N+1) int, cursor : N int, bsum : 256 int, srcs : E int
    char* w = (char*)d_ws;
    float*          Q       = (float*)w;           w += (size_t)N * DIM * sizeof(float);
    unsigned short* KV      = (unsigned short*)w;  w += (size_t)N * 256 * sizeof(unsigned short);
    unsigned short* WT      = (unsigned short*)w;  w += (size_t)384 * DIM * sizeof(unsigned short);
    float*          bias384 = (float*)w;           w += 384 * sizeof(float);
    int*            offs    = (int*)w;             w += (size_t)(N + 1) * sizeof(int);
    int*            cursor  = (int*)w;             w += (size_t)N * sizeof(int);
    int*            bsum    = (int*)w;             w += 256 * sizeof(int);
    int*            srcs    = (int*)w;

    hipMemsetAsync(offs, 0, (size_t)(N + 1) * sizeof(int), stream);

    convert_w_kernel<<<(384 * DIM) / 256, 256, 0, stream>>>(WQ, bQ, WK, bK, WV, bV,
                                                            WT, bias384);
    qkv_mfma_kernel<<<(N + 63) / 64, 256, 0, stream>>>(h, WT, bias384, Q, KV, N);
    hist_kernel<<<(E + 255) / 256, 256, 0, stream>>>(dst, offs, E);
    scan_blocks_kernel<<<NB, 256, 0, stream>>>(offs, bsum, N);
    scan_bsum_kernel<<<1, 256, 0, stream>>>(bsum, NB);
    scan_fixup_kernel<<<NB, 256, 0, stream>>>(offs, cursor, bsum, N, E);
    scatter_kernel<<<(E + 255) / 256, 256, 0, stream>>>(src, dst, cursor, srcs, E);
    aggregate_kernel<<<(N + 3) / 4, 256, 0, stream>>>(offs, srcs, Q,
                                                      (const unsigned*)KV, out, N);
}

// Round 4
// 265.935 us; speedup vs baseline: 2.4173x; 1.0404x over previous
//
#include <hip/hip_runtime.h>
#include <math.h>

// Problem constants: IN_DIM=128, HEADS=8, HEAD_DIM=16, HEADS*HEAD_DIM=128.
#define DIM 128
#define N_HEADS 8
#define HD 16

typedef __attribute__((ext_vector_type(8))) short bf16x8;   // MFMA A/B frag (4 VGPRs)
typedef __attribute__((ext_vector_type(4))) float f32x4;    // MFMA C/D frag

// ---------------------------------------------------------------------------
// bf16 helpers (RNE pack, cheap unpack)
// ---------------------------------------------------------------------------
__device__ __forceinline__ unsigned bf16pack2(float a, float b) {
    unsigned ua = __builtin_bit_cast(unsigned, a);
    unsigned ub = __builtin_bit_cast(unsigned, b);
    ua = (ua + 0x7FFFu + ((ua >> 16) & 1u)) >> 16;
    ub = (ub + 0x7FFFu + ((ub >> 16) & 1u)) >> 16;
    return ua | (ub << 16);
}
__device__ __forceinline__ float bf16lo(unsigned p) {
    return __builtin_bit_cast(float, p << 16);
}
__device__ __forceinline__ float bf16hi(unsigned p) {
    return __builtin_bit_cast(float, p & 0xFFFF0000u);
}

// ---------------------------------------------------------------------------
// Fused: convert_w (blocks [0,192)) || hist (blocks [192, 192+ceil(E/256)))
// convert: WT[c][k] = bf16(W_m[k][c&127]), bias384[c]; hist: offs[dst[e]]++.
// ---------------------------------------------------------------------------
__global__ __launch_bounds__(256)
void convert_hist_kernel(const float* __restrict__ WQ, const float* __restrict__ bQ,
                         const float* __restrict__ WK, const float* __restrict__ bK,
                         const float* __restrict__ WV, const float* __restrict__ bV,
                         unsigned short* __restrict__ WT, float* __restrict__ bias384,
                         const int* __restrict__ dst, int* __restrict__ offs,
                         int nConv, int E)
{
    if ((int)blockIdx.x < nConv) {
        int idx = blockIdx.x * 256 + threadIdx.x;       // 0..49151
        int c = idx >> 7, k = idx & 127;
        const float* W; const float* b; int col = c & 127;
        if (c < 128)      { W = WQ; b = bQ; }
        else if (c < 256) { W = WK; b = bK; }
        else              { W = WV; b = bV; }
        float v = W[k * DIM + col];
        WT[(size_t)c * DIM + k] = (unsigned short)(bf16pack2(v, 0.0f) & 0xFFFFu);
        if (k == 0) bias384[c] = b[col];
    } else {
        int e = ((int)blockIdx.x - nConv) * 256 + threadIdx.x;
        if (e < E) atomicAdd(&offs[dst[e]], 1);
    }
}

// ---------------------------------------------------------------------------
// Block-local exclusive scan of offs, block totals to bsum.
// ---------------------------------------------------------------------------
__global__ __launch_bounds__(256)
void scan_blocks_kernel(int* __restrict__ offs, int* __restrict__ bsum, int N)
{
    __shared__ int sd[256];
    const int t = threadIdx.x;
    const int i = blockIdx.x * 256 + t;
    int v = (i < N) ? offs[i] : 0;
    sd[t] = v;
    __syncthreads();
    #pragma unroll
    for (int o = 1; o < 256; o <<= 1) {
        int x = (t >= o) ? sd[t - o] : 0;
        __syncthreads();
        sd[t] += x;
        __syncthreads();
    }
    int incl = sd[t];
    if (i < N) offs[i] = incl - v;            // block-local exclusive
    if (t == 255) bsum[blockIdx.x] = incl;    // block total
}

// ---------------------------------------------------------------------------
// Fixup with folded bsum-scan: each block reduces bsum[0..bid) in LDS, then
// adds the base to its 256 offs entries; mirrors to cursor.
// ---------------------------------------------------------------------------
__global__ __launch_bounds__(256)
void scan_fixup_kernel(int* __restrict__ offs, int* __restrict__ cursor,
                       const int* __restrict__ bsum, int nb, int N, int E)
{
    __shared__ int sd[256];
    const int t = threadIdx.x;
    sd[t] = (t < nb && t < (int)blockIdx.x) ? bsum[t] : 0;
    __syncthreads();
    #pragma unroll
    for (int o = 128; o > 0; o >>= 1) {
        if (t < o) sd[t] += sd[t + o];
        __syncthreads();
    }
    const int base = sd[0];
    int i = blockIdx.x * 256 + t;
    if (i < N) {
        int v = offs[i] + base;
        offs[i]   = v;
        cursor[i] = v;
    }
    if (i == 0) offs[N] = E;
}

// ---------------------------------------------------------------------------
// Fused: qkv via bf16 MFMA (blocks [0,nQkv)) || scatter (rest).
//
// qkv: block = 4 waves covers 64 nodes x 384 cols; wave w owns cols
// [w*96,(w+1)*96). h tile bf16 in LDS (stride 136). acc bias-init.
// Outputs: Q fp32 [N,128]; KV2 interleaved dwords: row n = 128 dwords,
// dword 2l = K bf16-pair (cols 2l,2l+1), dword 2l+1 = V bf16-pair.
// A frag: A[m=lane&15][k=quad*8+j]; B frag from WT row; C/D: col=lane&15,
// row=quad*4+reg. Epilogue packs adjacent cols via __shfl_xor(1).
//
// scatter: pos = cursor[dst[e]]++; srcs[pos] = src[e].
// ---------------------------------------------------------------------------
__global__ __launch_bounds__(256)
void qkv_scatter_kernel(const float* __restrict__ h,
                        const unsigned short* __restrict__ WT,
                        const float* __restrict__ bias384,
                        float* __restrict__ Q, unsigned* __restrict__ KVd,
                        const int* __restrict__ src, const int* __restrict__ dst,
                        int* __restrict__ cursor, int* __restrict__ srcs,
                        int nQkv, int N, int E)
{
    __shared__ unsigned short hs[64 * 136];
    const int tid = threadIdx.x;

    if ((int)blockIdx.x >= nQkv) {
        int e = ((int)blockIdx.x - nQkv) * 256 + tid;
        if (e < E) {
            int d   = dst[e];
            int pos = atomicAdd(&cursor[d], 1);
            srcs[pos] = src[e];
        }
        return;
    }

    const int n0 = blockIdx.x * 64;

    // ---- stage 64x128 h tile as bf16 -------------------------------------
    #pragma unroll
    for (int i = 0; i < 4; ++i) {
        int lin  = i * 256 + tid;          // 0..1023
        int node = lin >> 4;               // 0..63
        int k0   = (lin & 15) * 8;         // 0..120
        int gn   = n0 + node;
        float4 a0, a1;
        if (gn < N) {
            a0 = *(const float4*)(h + (size_t)gn * DIM + k0);
            a1 = *(const float4*)(h + (size_t)gn * DIM + k0 + 4);
        } else {
            a0 = make_float4(0.f, 0.f, 0.f, 0.f);
            a1 = a0;
        }
        uint4 p = make_uint4(bf16pack2(a0.x, a0.y), bf16pack2(a0.z, a0.w),
                             bf16pack2(a1.x, a1.y), bf16pack2(a1.z, a1.w));
        *(uint4*)(hs + node * 136 + k0) = p;
    }
    __syncthreads();

    const int wave   = tid >> 6;
    const int l      = tid & 63;
    const int lane16 = l & 15;
    const int quad   = l >> 4;
    const int wc0    = wave * 96;

    f32x4 acc[4][6];
    #pragma unroll
    for (int ct = 0; ct < 6; ++ct) {
        float bv = bias384[wc0 + ct * 16 + lane16];
        #pragma unroll
        for (int rt = 0; rt < 4; ++rt)
            acc[rt][ct] = (f32x4){bv, bv, bv, bv};
    }

    #pragma unroll
    for (int ks = 0; ks < 4; ++ks) {
        bf16x8 a[4], b[6];
        #pragma unroll
        for (int rt = 0; rt < 4; ++rt)
            a[rt] = *(const bf16x8*)(hs + (rt * 16 + lane16) * 136 + ks * 32 + quad * 8);
        #pragma unroll
        for (int ct = 0; ct < 6; ++ct)
            b[ct] = *(const bf16x8*)(WT + (size_t)(wc0 + ct * 16 + lane16) * DIM
                                         + ks * 32 + quad * 8);
        #pragma unroll
        for (int rt = 0; rt < 4; ++rt)
            #pragma unroll
            for (int ct = 0; ct < 6; ++ct)
                acc[rt][ct] = __builtin_amdgcn_mfma_f32_16x16x32_bf16(
                    a[rt], b[ct], acc[rt][ct], 0, 0, 0);
    }

    const bool evenlane = (lane16 & 1) == 0;
    #pragma unroll
    for (int rt = 0; rt < 4; ++rt) {
        #pragma unroll
        for (int ct = 0; ct < 6; ++ct) {
            int col = wc0 + ct * 16 + lane16;
            #pragma unroll
            for (int i = 0; i < 4; ++i) {
                float v  = acc[rt][ct][i];
                float vn = __shfl_xor(v, 1);
                int gn = n0 + rt * 16 + quad * 4 + i;
                if (evenlane && gn < N) {
                    if (col < 128) {
                        *(float2*)(Q + (size_t)gn * DIM + col) = make_float2(v, vn);
                    } else if (col < 256) {
                        // K pair for cols (c,c+1) -> dword (c-128) (even)
                        KVd[(size_t)gn * 128 + (col - 128)] = bf16pack2(v, vn);
                    } else {
                        // V pair -> dword (c-256)+1 (odd)
                        KVd[(size_t)gn * 128 + (col - 256) + 1] = bf16pack2(v, vn);
                    }
                }
            }
        }
    }
}

// ---------------------------------------------------------------------------
// Aggregate: one wave per dst node; lane owns elements 2l,2l+1 (head l>>3).
// Per edge: ONE dwordx2 gather {K pair, V pair}, 8-lane shuffle dot,
// exp(clamp/4), register accumulate. 4-edge unroll for MLP. Single store.
// ---------------------------------------------------------------------------
__device__ __forceinline__ void agg_step(uint2 kv, float2 q,
                                         float& ax, float& ay, float& zs)
{
    float p = bf16lo(kv.x) * q.x + bf16hi(kv.x) * q.y;
    p += __shfl_xor(p, 4);
    p += __shfl_xor(p, 2);
    p += __shfl_xor(p, 1);
    p = fminf(fmaxf(p * 0.25f, -5.0f), 5.0f);
    float w = __expf(p);
    ax += w * bf16lo(kv.y);
    ay += w * bf16hi(kv.y);
    zs += w;
}

__global__ __launch_bounds__(256)
void aggregate_kernel(const int* __restrict__ offs, const int* __restrict__ srcs,
                      const float* __restrict__ Q, const unsigned* __restrict__ KVd,
                      float* __restrict__ out, int N)
{
    const int node = blockIdx.x * 4 + (threadIdx.x >> 6);
    if (node >= N) return;
    const int l = threadIdx.x & 63;

    const float2 q = *(const float2*)(Q + (size_t)node * DIM + 2 * l);
    const int start = offs[node];
    const int end   = offs[node + 1];

    float ax = 0.0f, ay = 0.0f, zs = 0.0f;

    int e = start;
    for (; e + 4 <= end; e += 4) {
        int s0 = srcs[e], s1 = srcs[e + 1], s2 = srcs[e + 2], s3 = srcs[e + 3];
        uint2 kv0 = *(const uint2*)(KVd + (size_t)s0 * 128 + 2 * l);
        uint2 kv1 = *(const uint2*)(KVd + (size_t)s1 * 128 + 2 * l);
        uint2 kv2 = *(const uint2*)(KVd + (size_t)s2 * 128 + 2 * l);
        uint2 kv3 = *(const uint2*)(KVd + (size_t)s3 * 128 + 2 * l);
        // interleave the four dot chains for ILP
        float p0 = bf16lo(kv0.x) * q.x + bf16hi(kv0.x) * q.y;
        float p1 = bf16lo(kv1.x) * q.x + bf16hi(kv1.x) * q.y;
        float p2 = bf16lo(kv2.x) * q.x + bf16hi(kv2.x) * q.y;
        float p3 = bf16lo(kv3.x) * q.x + bf16hi(kv3.x) * q.y;
        p0 += __shfl_xor(p0, 4); p1 += __shfl_xor(p1, 4);
        p2 += __shfl_xor(p2, 4); p3 += __shfl_xor(p3, 4);
        p0 += __shfl_xor(p0, 2); p1 += __shfl_xor(p1, 2);
        p2 += __shfl_xor(p2, 2); p3 += __shfl_xor(p3, 2);
        p0 += __shfl_xor(p0, 1); p1 += __shfl_xor(p1, 1);
        p2 += __shfl_xor(p2, 1); p3 += __shfl_xor(p3, 1);
        p0 = fminf(fmaxf(p0 * 0.25f, -5.0f), 5.0f);
        p1 = fminf(fmaxf(p1 * 0.25f, -5.0f), 5.0f);
        p2 = fminf(fmaxf(p2 * 0.25f, -5.0f), 5.0f);
        p3 = fminf(fmaxf(p3 * 0.25f, -5.0f), 5.0f);
        float w0 = __expf(p0), w1 = __expf(p1), w2 = __expf(p2), w3 = __expf(p3);
        ax += w0 * bf16lo(kv0.y); ay += w0 * bf16hi(kv0.y); zs += w0;
        ax += w1 * bf16lo(kv1.y); ay += w1 * bf16hi(kv1.y); zs += w1;
        ax += w2 * bf16lo(kv2.y); ay += w2 * bf16hi(kv2.y); zs += w2;
        ax += w3 * bf16lo(kv3.y); ay += w3 * bf16hi(kv3.y); zs += w3;
    }
    for (; e < end; ++e) {
        int s0 = srcs[e];
        uint2 kv0 = *(const uint2*)(KVd + (size_t)s0 * 128 + 2 * l);
        agg_step(kv0, q, ax, ay, zs);
    }

    float inv = (zs > 0.0f) ? (1.0f / zs) : 0.0f;
    *(float2*)(out + (size_t)node * DIM + 2 * l) = make_float2(ax * inv, ay * inv);
}

// ---------------------------------------------------------------------------
extern "C" void kernel_launch(void* const* d_in, const int* in_sizes, int n_in,
                              void* d_out, int out_size, void* d_ws, size_t ws_size,
                              hipStream_t stream) {
    const float* h   = (const float*)d_in[0];
    const int*   src = (const int*)  d_in[1];
    const int*   dst = (const int*)  d_in[2];
    const float* WQ  = (const float*)d_in[3];
    const float* bQ  = (const float*)d_in[4];
    const float* WK  = (const float*)d_in[5];
    const float* bK  = (const float*)d_in[6];
    const float* WV  = (const float*)d_in[7];
    const float* bV  = (const float*)d_in[8];
    float* out = (float*)d_out;

    const int N  = in_sizes[0] / DIM;
    const int E  = in_sizes[1];
    const int NB = (N + 255) / 256;       // 196 scan blocks (must be <= 256)
    const int EB = (E + 255) / 256;       // 3125 edge blocks
    const int nConv = (384 * DIM) / 256;  // 192
    const int nQkv  = (N + 63) / 64;      // 782

    // Workspace: Q (25.6MB) | KV2 (25.6MB) | WT | bias384 | offs | cursor | bsum | srcs
    char* w = (char*)d_ws;
    float*          Q       = (float*)w;           w += (size_t)N * DIM * sizeof(float);
    unsigned*       KVd     = (unsigned*)w;        w += (size_t)N * 128 * sizeof(unsigned);
    unsigned short* WT      = (unsigned short*)w;  w += (size_t)384 * DIM * sizeof(unsigned short);
    float*          bias384 = (float*)w;           w += 384 * sizeof(float);
    int*            offs    = (int*)w;             w += (size_t)(N + 1) * sizeof(int);
    int*            cursor  = (int*)w;             w += (size_t)N * sizeof(int);
    int*            bsum    = (int*)w;             w += 256 * sizeof(int);
    int*            srcs    = (int*)w;

    hipMemsetAsync(offs, 0, (size_t)(N + 1) * sizeof(int), stream);

    convert_hist_kernel<<<nConv + EB, 256, 0, stream>>>(WQ, bQ, WK, bK, WV, bV,
                                                        WT, bias384, dst, offs,
                                                        nConv, E);
    scan_blocks_kernel<<<NB, 256, 0, stream>>>(offs, bsum, N);
    scan_fixup_kernel<<<NB, 256, 0, stream>>>(offs, cursor, bsum, NB, N, E);
    qkv_scatter_kernel<<<nQkv + EB, 256, 0, stream>>>(h, WT, bias384, Q, KVd,
                                                      src, dst, cursor, srcs,
                                                      nQkv, N, E);
    aggregate_kernel<<<(N + 3) / 4, 256, 0, stream>>>(offs, srcs, Q, KVd, out, N);
}

// Round 5
// 263.442 us; speedup vs baseline: 2.4402x; 1.0095x over previous
//
#include <hip/hip_runtime.h>
#include <math.h>

// Problem constants: IN_DIM=128, HEADS=8, HEAD_DIM=16, HEADS*HEAD_DIM=128.
#define DIM 128
#define N_HEADS 8
#define HD 16

typedef __attribute__((ext_vector_type(8))) short bf16x8;   // MFMA A/B frag (4 VGPRs)
typedef __attribute__((ext_vector_type(4))) float f32x4;    // MFMA C/D frag

// ---------------------------------------------------------------------------
// bf16 helpers (RNE pack, cheap unpack)
// ---------------------------------------------------------------------------
__device__ __forceinline__ unsigned bf16pack2(float a, float b) {
    unsigned ua = __builtin_bit_cast(unsigned, a);
    unsigned ub = __builtin_bit_cast(unsigned, b);
    ua = (ua + 0x7FFFu + ((ua >> 16) & 1u)) >> 16;
    ub = (ub + 0x7FFFu + ((ub >> 16) & 1u)) >> 16;
    return ua | (ub << 16);
}
__device__ __forceinline__ float bf16lo(unsigned p) {
    return __builtin_bit_cast(float, p << 16);
}
__device__ __forceinline__ float bf16hi(unsigned p) {
    return __builtin_bit_cast(float, p & 0xFFFF0000u);
}

// ---------------------------------------------------------------------------
// Fused: convert_w (blocks [0,192)) || hist (blocks [192, 192+ceil(E/256)))
// ---------------------------------------------------------------------------
__global__ __launch_bounds__(256)
void convert_hist_kernel(const float* __restrict__ WQ, const float* __restrict__ bQ,
                         const float* __restrict__ WK, const float* __restrict__ bK,
                         const float* __restrict__ WV, const float* __restrict__ bV,
                         unsigned short* __restrict__ WT, float* __restrict__ bias384,
                         const int* __restrict__ dst, int* __restrict__ offs,
                         int nConv, int E)
{
    if ((int)blockIdx.x < nConv) {
        int idx = blockIdx.x * 256 + threadIdx.x;       // 0..49151
        int c = idx >> 7, k = idx & 127;
        const float* W; const float* b; int col = c & 127;
        if (c < 128)      { W = WQ; b = bQ; }
        else if (c < 256) { W = WK; b = bK; }
        else              { W = WV; b = bV; }
        float v = W[k * DIM + col];
        WT[(size_t)c * DIM + k] = (unsigned short)(bf16pack2(v, 0.0f) & 0xFFFFu);
        if (k == 0) bias384[c] = b[col];
    } else {
        int e = ((int)blockIdx.x - nConv) * 256 + threadIdx.x;
        if (e < E) atomicAdd(&offs[dst[e]], 1);
    }
}

// ---------------------------------------------------------------------------
// Block-local exclusive scan of offs, block totals to bsum.
// ---------------------------------------------------------------------------
__global__ __launch_bounds__(256)
void scan_blocks_kernel(int* __restrict__ offs, int* __restrict__ bsum, int N)
{
    __shared__ int sd[256];
    const int t = threadIdx.x;
    const int i = blockIdx.x * 256 + t;
    int v = (i < N) ? offs[i] : 0;
    sd[t] = v;
    __syncthreads();
    #pragma unroll
    for (int o = 1; o < 256; o <<= 1) {
        int x = (t >= o) ? sd[t - o] : 0;
        __syncthreads();
        sd[t] += x;
        __syncthreads();
    }
    int incl = sd[t];
    if (i < N) offs[i] = incl - v;            // block-local exclusive
    if (t == 255) bsum[blockIdx.x] = incl;    // block total
}

// ---------------------------------------------------------------------------
// Fixup with folded bsum-scan: each block reduces bsum[0..bid) in LDS, then
// adds the base to its 256 offs entries; mirrors to cursor.
// ---------------------------------------------------------------------------
__global__ __launch_bounds__(256)
void scan_fixup_kernel(int* __restrict__ offs, int* __restrict__ cursor,
                       const int* __restrict__ bsum, int nb, int N, int E)
{
    __shared__ int sd[256];
    const int t = threadIdx.x;
    sd[t] = (t < nb && t < (int)blockIdx.x) ? bsum[t] : 0;
    __syncthreads();
    #pragma unroll
    for (int o = 128; o > 0; o >>= 1) {
        if (t < o) sd[t] += sd[t + o];
        __syncthreads();
    }
    const int base = sd[0];
    int i = blockIdx.x * 256 + t;
    if (i < N) {
        int v = offs[i] + base;
        offs[i]   = v;
        cursor[i] = v;
    }
    if (i == 0) offs[N] = E;
}

// ---------------------------------------------------------------------------
// Scatter (standalone: 8 VGPR, no LDS -> full occupancy; its dirty srcs
// lines stay in L2 instead of thrashing against qkv's streaming stores).
// ---------------------------------------------------------------------------
__global__ __launch_bounds__(256)
void scatter_kernel(const int* __restrict__ src, const int* __restrict__ dst,
                    int* __restrict__ cursor, int* __restrict__ srcs, int E)
{
    int e = blockIdx.x * 256 + threadIdx.x;
    if (e < E) {
        int d   = dst[e];
        int pos = atomicAdd(&cursor[d], 1);
        srcs[pos] = src[e];
    }
}

// ---------------------------------------------------------------------------
// QKV via bf16 MFMA 16x16x32, SWAPPED operands: A = WT (m = output col),
// B = h tile (n = node). D[m=col][n=node]: col = quad*4 + reg (4 consecutive
// cols per lane!), node = lane&15. Epilogue: one float4 store (Q) or two
// dword bf16-pair stores (KV) per acc tile -- no shuffles, no predication,
// 4 quads' 16B chunks form whole 64B lines.
// Block = 4 waves = 64 nodes x 384 cols; wave w owns cols [w*96,(w+1)*96).
// KV layout (dwords): row n = 128 dwords; dword 2l = K pair (cols 2l,2l+1),
// dword 2l+1 = V pair (cols 2l,2l+1).
// ---------------------------------------------------------------------------
__global__ __launch_bounds__(256)
void qkv_mfma_kernel(const float* __restrict__ h,
                     const unsigned short* __restrict__ WT,
                     const float* __restrict__ bias384,
                     float* __restrict__ Q, unsigned* __restrict__ KVd,
                     int N)
{
    __shared__ unsigned short hs[64 * 136];
    const int tid = threadIdx.x;
    const int n0  = blockIdx.x * 64;

    // ---- stage 64x128 h tile as bf16 -------------------------------------
    #pragma unroll
    for (int i = 0; i < 4; ++i) {
        int lin  = i * 256 + tid;          // 0..1023
        int node = lin >> 4;               // 0..63
        int k0   = (lin & 15) * 8;         // 0..120
        int gn   = n0 + node;
        float4 a0, a1;
        if (gn < N) {
            a0 = *(const float4*)(h + (size_t)gn * DIM + k0);
            a1 = *(const float4*)(h + (size_t)gn * DIM + k0 + 4);
        } else {
            a0 = make_float4(0.f, 0.f, 0.f, 0.f);
            a1 = a0;
        }
        uint4 p = make_uint4(bf16pack2(a0.x, a0.y), bf16pack2(a0.z, a0.w),
                             bf16pack2(a1.x, a1.y), bf16pack2(a1.z, a1.w));
        *(uint4*)(hs + node * 136 + k0) = p;
    }
    __syncthreads();

    const int wave   = tid >> 6;
    const int l      = tid & 63;
    const int lane16 = l & 15;
    const int quad   = l >> 4;
    const int wc0    = wave * 96;

    // acc[ct][rt]: cols (wc0+ct*16+quad*4 .. +3), node n0+rt*16+lane16
    f32x4 acc[6][4];
    #pragma unroll
    for (int ct = 0; ct < 6; ++ct) {
        float4 bv = *(const float4*)(bias384 + wc0 + ct * 16 + quad * 4);
        #pragma unroll
        for (int rt = 0; rt < 4; ++rt)
            acc[ct][rt] = (f32x4){bv.x, bv.y, bv.z, bv.w};
    }

    #pragma unroll
    for (int ks = 0; ks < 4; ++ks) {
        bf16x8 a[6], b[4];
        #pragma unroll
        for (int ct = 0; ct < 6; ++ct)
            a[ct] = *(const bf16x8*)(WT + (size_t)(wc0 + ct * 16 + lane16) * DIM
                                         + ks * 32 + quad * 8);
        #pragma unroll
        for (int rt = 0; rt < 4; ++rt)
            b[rt] = *(const bf16x8*)(hs + (rt * 16 + lane16) * 136 + ks * 32 + quad * 8);
        #pragma unroll
        for (int ct = 0; ct < 6; ++ct)
            #pragma unroll
            for (int rt = 0; rt < 4; ++rt)
                acc[ct][rt] = __builtin_amdgcn_mfma_f32_16x16x32_bf16(
                    a[ct], b[rt], acc[ct][rt], 0, 0, 0);
    }

    // ---- epilogue: direct vector stores, no shuffles ---------------------
    #pragma unroll
    for (int ct = 0; ct < 6; ++ct) {
        const int col = wc0 + ct * 16 + quad * 4;   // multiple of 4
        #pragma unroll
        for (int rt = 0; rt < 4; ++rt) {
            int gn = n0 + rt * 16 + lane16;
            if (gn >= N) continue;
            f32x4 v = acc[ct][rt];
            if (col < 128) {
                *(float4*)(Q + (size_t)gn * DIM + col) =
                    make_float4(v[0], v[1], v[2], v[3]);
            } else if (col < 256) {
                int c = col - 128;                 // K pairs -> dwords c, c+2
                KVd[(size_t)gn * 128 + c]     = bf16pack2(v[0], v[1]);
                KVd[(size_t)gn * 128 + c + 2] = bf16pack2(v[2], v[3]);
            } else {
                int c = col - 256;                 // V pairs -> dwords c+1, c+3
                KVd[(size_t)gn * 128 + c + 1] = bf16pack2(v[0], v[1]);
                KVd[(size_t)gn * 128 + c + 3] = bf16pack2(v[2], v[3]);
            }
        }
    }
}

// ---------------------------------------------------------------------------
// Aggregate: one wave per dst node; lane owns elements 2l,2l+1 (head l>>3).
// Per edge: ONE dwordx2 gather {K pair, V pair}, 8-lane shuffle dot,
// exp(clamp/4), register accumulate. 8-edge unroll (8 outstanding gathers
// per lane) + 4 + scalar tail. Single divided store, zero atomics.
// ---------------------------------------------------------------------------
__device__ __forceinline__ void agg_step(uint2 kv, float2 q,
                                         float& ax, float& ay, float& zs)
{
    float p = bf16lo(kv.x) * q.x + bf16hi(kv.x) * q.y;
    p += __shfl_xor(p, 4);
    p += __shfl_xor(p, 2);
    p += __shfl_xor(p, 1);
    p = fminf(fmaxf(p * 0.25f, -5.0f), 5.0f);
    float w = __expf(p);
    ax += w * bf16lo(kv.y);
    ay += w * bf16hi(kv.y);
    zs += w;
}

__global__ __launch_bounds__(256)
void aggregate_kernel(const int* __restrict__ offs, const int* __restrict__ srcs,
                      const float* __restrict__ Q, const unsigned* __restrict__ KVd,
                      float* __restrict__ out, int N)
{
    const int node = blockIdx.x * 4 + (threadIdx.x >> 6);
    if (node >= N) return;
    const int l = threadIdx.x & 63;

    const float2 q = *(const float2*)(Q + (size_t)node * DIM + 2 * l);
    const int start = offs[node];
    const int end   = offs[node + 1];

    float ax = 0.0f, ay = 0.0f, zs = 0.0f;

    int e = start;
    for (; e + 8 <= end; e += 8) {
        uint2 kv[8];
        #pragma unroll
        for (int j = 0; j < 8; ++j) {
            int s = srcs[e + j];
            kv[j] = *(const uint2*)(KVd + (size_t)s * 128 + 2 * l);
        }
        float p[8];
        #pragma unroll
        for (int j = 0; j < 8; ++j)
            p[j] = bf16lo(kv[j].x) * q.x + bf16hi(kv[j].x) * q.y;
        #pragma unroll
        for (int j = 0; j < 8; ++j) p[j] += __shfl_xor(p[j], 4);
        #pragma unroll
        for (int j = 0; j < 8; ++j) p[j] += __shfl_xor(p[j], 2);
        #pragma unroll
        for (int j = 0; j < 8; ++j) p[j] += __shfl_xor(p[j], 1);
        #pragma unroll
        for (int j = 0; j < 8; ++j) {
            float pc = fminf(fmaxf(p[j] * 0.25f, -5.0f), 5.0f);
            float w  = __expf(pc);
            ax += w * bf16lo(kv[j].y);
            ay += w * bf16hi(kv[j].y);
            zs += w;
        }
    }
    for (; e + 4 <= end; e += 4) {
        uint2 kv[4];
        #pragma unroll
        for (int j = 0; j < 4; ++j) {
            int s = srcs[e + j];
            kv[j] = *(const uint2*)(KVd + (size_t)s * 128 + 2 * l);
        }
        float p[4];
        #pragma unroll
        for (int j = 0; j < 4; ++j)
            p[j] = bf16lo(kv[j].x) * q.x + bf16hi(kv[j].x) * q.y;
        #pragma unroll
        for (int j = 0; j < 4; ++j) p[j] += __shfl_xor(p[j], 4);
        #pragma unroll
        for (int j = 0; j < 4; ++j) p[j] += __shfl_xor(p[j], 2);
        #pragma unroll
        for (int j = 0; j < 4; ++j) p[j] += __shfl_xor(p[j], 1);
        #pragma unroll
        for (int j = 0; j < 4; ++j) {
            float pc = fminf(fmaxf(p[j] * 0.25f, -5.0f), 5.0f);
            float w  = __expf(pc);
            ax += w * bf16lo(kv[j].y);
            ay += w * bf16hi(kv[j].y);
            zs += w;
        }
    }
    for (; e < end; ++e) {
        int s0 = srcs[e];
        uint2 kv0 = *(const uint2*)(KVd + (size_t)s0 * 128 + 2 * l);
        agg_step(kv0, q, ax, ay, zs);
    }

    float inv = (zs > 0.0f) ? (1.0f / zs) : 0.0f;
    *(float2*)(out + (size_t)node * DIM + 2 * l) = make_float2(ax * inv, ay * inv);
}

// ---------------------------------------------------------------------------
extern "C" void kernel_launch(void* const* d_in, const int* in_sizes, int n_in,
                              void* d_out, int out_size, void* d_ws, size_t ws_size,
                              hipStream_t stream) {
    const float* h   = (const float*)d_in[0];
    const int*   src = (const int*)  d_in[1];
    const int*   dst = (const int*)  d_in[2];
    const float* WQ  = (const float*)d_in[3];
    const float* bQ  = (const float*)d_in[4];
    const float* WK  = (const float*)d_in[5];
    const float* bK  = (const float*)d_in[6];
    const float* WV  = (const float*)d_in[7];
    const float* bV  = (const float*)d_in[8];
    float* out = (float*)d_out;

    const int N  = in_sizes[0] / DIM;
    const int E  = in_sizes[1];
    const int NB = (N + 255) / 256;       // 196 scan blocks (must be <= 256)
    const int EB = (E + 255) / 256;       // 3125 edge blocks
    const int nConv = (384 * DIM) / 256;  // 192

    // Workspace: Q (25.6MB) | KV2 (25.6MB) | WT | bias384 | offs | cursor | bsum | srcs
    char* w = (char*)d_ws;
    float*          Q       = (float*)w;           w += (size_t)N * DIM * sizeof(float);
    unsigned*       KVd     = (unsigned*)w;        w += (size_t)N * 128 * sizeof(unsigned);
    unsigned short* WT      = (unsigned short*)w;  w += (size_t)384 * DIM * sizeof(unsigned short);
    float*          bias384 = (float*)w;           w += 384 * sizeof(float);
    int*            offs    = (int*)w;             w += (size_t)(N + 1) * sizeof(int);
    int*            cursor  = (int*)w;             w += (size_t)N * sizeof(int);
    int*            bsum    = (int*)w;             w += 256 * sizeof(int);
    int*            srcs    = (int*)w;

    hipMemsetAsync(offs, 0, (size_t)(N + 1) * sizeof(int), stream);

    convert_hist_kernel<<<nConv + EB, 256, 0, stream>>>(WQ, bQ, WK, bK, WV, bV,
                                                        WT, bias384, dst, offs,
                                                        nConv, E);
    scan_blocks_kernel<<<NB, 256, 0, stream>>>(offs, bsum, N);
    scan_fixup_kernel<<<NB, 256, 0, stream>>>(offs, cursor, bsum, NB, N, E);
    scatter_kernel<<<EB, 256, 0, stream>>>(src, dst, cursor, srcs, E);
    qkv_mfma_kernel<<<(N + 63) / 64, 256, 0, stream>>>(h, WT, bias384, Q, KVd, N);
    aggregate_kernel<<<(N + 3) / 4, 256, 0, stream>>>(offs, srcs, Q, KVd, out, N);
}